// Round 8
// baseline (289.362 us; speedup 1.0000x reference)
//
#include <hip/hip_runtime.h>

// ---------------------------------------------------------------------------
// GIN forward. R8: L2-resident sliced gather, take 2. R4 proved slicing gets
// residency (FETCH 191->39MB) but used 4B loads (8x instructions, 108us).
// R7 proved row-major is fabric-floored at ~3.5TB/s (62us). Now: slice-major
// [NS][NN][32ch] tables, 4 lanes x 16B per 64B neighbor row, 4 neighbors per
// 16-lane group -> same load-instruction count as row-major + L2 residency.
// GEMMs read A slice-major (kt/32 = slice); GEMM2 writes slice-major.
// ---------------------------------------------------------------------------

typedef __attribute__((ext_vector_type(8))) short bf16x8;
typedef __attribute__((ext_vector_type(4))) float f32x4;

__device__ __forceinline__ float bf2f(unsigned short u) {
  unsigned v = ((unsigned)u) << 16;
  return __builtin_bit_cast(float, v);
}
__device__ __forceinline__ unsigned short f2bf(float f) {
  unsigned u = __builtin_bit_cast(unsigned, f);
  u += 0x7fffu + ((u >> 16) & 1u);
  return (unsigned short)(u >> 16);
}

__device__ __forceinline__ void async16(const void* g, void* l) {
  __builtin_amdgcn_global_load_lds(
      (const __attribute__((address_space(1))) void*)g,
      (__attribute__((address_space(3))) void*)l, 16, 0, 0);
}

static const int NN = 50000;
static const int NE = 800000;
static const int SCAN_NB = 49;             // ceil(50000/1024)
static const int NB16 = NN / 16;           // 3125 node-blocks of 16

// --- fused prep: weight transpose+cast | x cast (slice-major) | histogram --
__global__ __launch_bounds__(256) void k_prep(
    const float* __restrict__ W1a, const float* __restrict__ W1b,
    const float* __restrict__ W2,  const float* __restrict__ W3,
    unsigned short* __restrict__ WT,
    const float* __restrict__ x, unsigned short* __restrict__ xbS,
    const int* __restrict__ ei, int* __restrict__ counts)
{
  int idx = blockIdx.x * 256 + threadIdx.x;
  if (idx < 196608) {
    const float* W; unsigned short* out; int K, N, li;
    if (idx < 32768)       { W = W1a; out = WT;          K = 128; N = 256; li = idx; }
    else if (idx < 98304)  { W = W1b; out = WT + 32768;  K = 256; N = 256; li = idx - 32768; }
    else if (idx < 163840) { W = W2;  out = WT + 98304;  K = 256; N = 256; li = idx - 98304; }
    else                   { W = W3;  out = WT + 163840; K = 256; N = 128; li = idx - 163840; }
    int n = li / K, k = li - n * K;
    out[li] = f2bf(W[k * N + n]);
  } else if (idx < 196608 + NN * 32) {     // NN*128/4 float4 units
    int i = idx - 196608;
    int node = i >> 5, u = i & 31;         // u: which float4 within the row
    int s = u >> 3, co = (u & 7) * 4;      // slice, channel offset in slice
    float4 v = reinterpret_cast<const float4*>(x)[i];
    ushort4 b; b.x = f2bf(v.x); b.y = f2bf(v.y); b.z = f2bf(v.z); b.w = f2bf(v.w);
    *reinterpret_cast<ushort4*>(xbS + ((size_t)s * NN + node) * 32 + co) = b;
  } else {
    int e = idx - 196608 - NN * 32;
    if (e < NE) atomicAdd(&counts[ei[NE + e]], 1);
  }
}

// --- scan phase A: per-block inclusive scan (Hillis-Steele in LDS) ---------
__global__ __launch_bounds__(1024) void k_scan_a(const int* __restrict__ counts,
    int* __restrict__ offs, int* __restrict__ bsum)
{
  __shared__ int sh[1024];
  const int t = threadIdx.x;
  int idx = blockIdx.x * 1024 + t;
  int c = (idx < NN) ? counts[idx] : 0;
  sh[t] = c;
  __syncthreads();
  int v = c;
  for (int off = 1; off < 1024; off <<= 1) {
    int tmp = (t >= off) ? sh[t - off] : 0;
    __syncthreads();
    v += tmp; sh[t] = v;
    __syncthreads();
  }
  if (idx < NN) offs[idx] = v - c;
  if (t == 1023) bsum[blockIdx.x] = v;
}

// --- scan phase B: add block bases; copy to cursor; offs[NN]=NE ------------
__global__ __launch_bounds__(1024) void k_scan_b(const int* __restrict__ bsum,
    int* __restrict__ offs, int* __restrict__ cursor)
{
  __shared__ int sb[64];
  const int t = threadIdx.x;
  if (t < SCAN_NB) sb[t] = bsum[t];
  __syncthreads();
  int base = 0;
  for (int j = 0; j < SCAN_NB; j++) base += (j < (int)blockIdx.x) ? sb[j] : 0;
  int idx = blockIdx.x * 1024 + t;
  if (idx < NN) { int o = offs[idx] + base; offs[idx] = o; cursor[idx] = o; }
  if (blockIdx.x == 0 && t == 0) offs[NN] = NE;
}

// --- scatter src ids into CSR order ---------------------------------------
__global__ __launch_bounds__(256) void k_scatter(const int* __restrict__ ei,
    int* __restrict__ cursor, int* __restrict__ srcs)
{
  int e = blockIdx.x * 256 + threadIdx.x;
  if (e >= NE) return;
  int dst = ei[NE + e];
  int pos = atomicAdd(&cursor[dst], 1);
  srcs[pos] = ei[e];
}

// --- sliced gather-aggregate v2 -------------------------------------------
// featS/outS: bf16 slice-major [NS][NN][32]. slice = blockIdx % NS -> XCD
// round-robin pins each 3.2MB slice to one XCD's L2. Per 16-lane node-group:
// sub = l>>2 (neighbor subset, stride 4), q = l&3 (16B quarter of 64B row).
// Cross-lane shfl_xor(4,8) reduce; self-term + store on sub==0 lanes.
// L1: self = (1+eps) * x_fp32[node] (row-major); else self = featS own row.
template<int NS, bool L1>
__global__ __launch_bounds__(256) void k_gather_sl(
    const int* __restrict__ offs, const int* __restrict__ srcs,
    const unsigned short* __restrict__ featS,
    const float* __restrict__ selfx, const float* __restrict__ eps,
    unsigned short* __restrict__ outS)
{
  const int s  = blockIdx.x % NS;
  const int nb = blockIdx.x / NS;
  const int g  = threadIdx.x >> 4;
  const int l  = threadIdx.x & 15;
  const int node = nb * 16 + g;
  const int sub = l >> 2;
  const int c0  = (l & 3) * 8;

  const unsigned short* tbl = featS + (size_t)s * NN * 32;

  float a[8];
#pragma unroll
  for (int j = 0; j < 8; j++) a[j] = 0.0f;

  int beg = __builtin_nontemporal_load(offs + node);
  int end = __builtin_nontemporal_load(offs + node + 1);

  int i = beg + sub;
  for (; i + 4 < end; i += 8) {            // 2-deep: both i and i+4 valid
    int s0 = __builtin_nontemporal_load(srcs + i);
    int s1 = __builtin_nontemporal_load(srcs + i + 4);
    bf16x8 v0 = *reinterpret_cast<const bf16x8*>(tbl + (size_t)s0 * 32 + c0);
    bf16x8 v1 = *reinterpret_cast<const bf16x8*>(tbl + (size_t)s1 * 32 + c0);
#pragma unroll
    for (int j = 0; j < 8; j++) a[j] += bf2f((unsigned short)v0[j]);
#pragma unroll
    for (int j = 0; j < 8; j++) a[j] += bf2f((unsigned short)v1[j]);
  }
  if (i < end) {
    int s0 = __builtin_nontemporal_load(srcs + i);
    bf16x8 v0 = *reinterpret_cast<const bf16x8*>(tbl + (size_t)s0 * 32 + c0);
#pragma unroll
    for (int j = 0; j < 8; j++) a[j] += bf2f((unsigned short)v0[j]);
  }

  // reduce across the 4 neighbor-subsets (lanes differing in bits 2-3)
#pragma unroll
  for (int j = 0; j < 8; j++) {
    a[j] += __shfl_xor(a[j], 4);
    a[j] += __shfl_xor(a[j], 8);
  }

  if (sub == 0) {
    if (L1) {
      float sc = 1.0f + eps[0];
      const float* sp = selfx + (size_t)node * (NS * 32) + s * 32 + c0;
      f32x4 v0 = __builtin_nontemporal_load(reinterpret_cast<const f32x4*>(sp));
      f32x4 v1 = __builtin_nontemporal_load(reinterpret_cast<const f32x4*>(sp + 4));
      a[0] += v0.x * sc; a[1] += v0.y * sc; a[2] += v0.z * sc; a[3] += v0.w * sc;
      a[4] += v1.x * sc; a[5] += v1.y * sc; a[6] += v1.z * sc; a[7] += v1.w * sc;
    } else {
      bf16x8 v = *reinterpret_cast<const bf16x8*>(tbl + (size_t)node * 32 + c0);
#pragma unroll
      for (int j = 0; j < 8; j++) a[j] += bf2f((unsigned short)v[j]);
    }
    bf16x8 o;
#pragma unroll
    for (int j = 0; j < 8; j++) o[j] = (short)f2bf(a[j]);
    __builtin_nontemporal_store(o,
        reinterpret_cast<bf16x8*>(outS + ((size_t)s * NN + node) * 32 + c0));
  }
}

// --- bf16 MFMA GEMM, double-buffered 2-phase pipeline ----------------------
// C = A * BT^T + bias. A row-major [M][K] (ASL=false) or slice-major
// [K/32][M][32] (ASL=true; K-step kt <-> slice kt/32, LDS layout identical).
// MODE 0: bf16 row-major out; 2: fp32 row-major out; 3: bf16 slice-major out.
template<bool RELU, int MODE, int BN_, bool ASL>
__global__ __launch_bounds__(BN_ * 2) void k_gemm(
    const unsigned short* __restrict__ A,
    const unsigned short* __restrict__ BT,
    const float* __restrict__ bias,
    unsigned short* __restrict__ Cb,
    float* __restrict__ Cf,
    int M, int K, int N)
{
  constexpr int WC = BN_ / 64;            // waves per col-band (2 or 4)
  constexpr int NW = 2 * WC;              // total waves (4 or 8)
  __shared__ unsigned short Asb[2][128 * 32];
  __shared__ unsigned short Bsb[2][BN_ * 32];
  const int tid = threadIdx.x;
  const int w = tid >> 6, l = tid & 63;
  const int bm = blockIdx.x * 128, bn = blockIdx.y * BN_;
  const int wr = w / WC, wc = w % WC;

  f32x4 acc[4][4];
#pragma unroll
  for (int m = 0; m < 4; m++)
#pragma unroll
    for (int n = 0; n < 4; n++) acc[m][n] = (f32x4)(0.0f);

  const int lr = l >> 2;                  // row within 16-row chunk
  const int lc = (l & 3) * 8;             // elem offset within 32

  auto stage = [&](int buf, int kt) {
#pragma unroll
    for (int ch = w; ch < 8; ch += NW) {          // A: 128 rows = 8 chunks
      int tr = ch * 16;
      int ar = bm + tr + lr; if (ar >= M) ar = M - 1;
      if (ASL)
        async16(A + ((size_t)(kt >> 5) * NN + ar) * 32 + lc, &Asb[buf][tr * 32]);
      else
        async16(A + (size_t)ar * K + kt + lc, &Asb[buf][tr * 32]);
    }
#pragma unroll
    for (int ch = w; ch < BN_ / 16; ch += NW) {   // B: BN_ rows
      int tr = ch * 16;
      int br = bn + tr + lr;                      // N % BN_ == 0
      async16(BT + (size_t)br * K + kt + lc, &Bsb[buf][tr * 32]);
    }
  };

  stage(0, 0);
  __syncthreads();

  int cur = 0;
  for (int kt = 0; kt < K; kt += 32) {
    if (kt + 32 < K) stage(cur ^ 1, kt + 32);

    bf16x8 af[4], bfr[4];
#pragma unroll
    for (int m = 0; m < 4; m++)
      af[m] = *reinterpret_cast<const bf16x8*>(
          &Asb[cur][(wr * 64 + m * 16 + (l & 15)) * 32 + (l >> 4) * 8]);
#pragma unroll
    for (int n = 0; n < 4; n++)
      bfr[n] = *reinterpret_cast<const bf16x8*>(
          &Bsb[cur][(wc * 64 + n * 16 + (l & 15)) * 32 + (l >> 4) * 8]);
#pragma unroll
    for (int m = 0; m < 4; m++)
#pragma unroll
      for (int n = 0; n < 4; n++)
        acc[m][n] = __builtin_amdgcn_mfma_f32_16x16x32_bf16(
            af[m], bfr[n], acc[m][n], 0, 0, 0);

    __syncthreads();                      // drains stage vmcnt + barriers
    cur ^= 1;
  }

  // epilogue: C/D layout col = lane&15, row = (lane>>4)*4 + reg  [m89]
#pragma unroll
  for (int m = 0; m < 4; m++) {
    int row0 = bm + wr * 64 + m * 16 + ((l >> 4) << 2);
#pragma unroll
    for (int n = 0; n < 4; n++) {
      int col = bn + wc * 64 + n * 16 + (l & 15);
      float bv = bias[col];
#pragma unroll
      for (int r = 0; r < 4; r++) {
        int row = row0 + r;
        if (row < M) {
          float v = acc[m][n][r] + bv;
          if (RELU) v = fmaxf(v, 0.0f);
          if (MODE == 0) Cb[(size_t)row * N + col] = f2bf(v);
          if (MODE == 2) Cf[(size_t)row * N + col] = v;
          if (MODE == 3)
            Cb[((size_t)(col >> 5) * NN + row) * 32 + (col & 31)] = f2bf(v);
        }
      }
    }
  }
}

// ---------------------------------------------------------------------------
// workspace layout (bytes); overlapped lifetimes:
//  xbS  [ 0.0 .. 12.8M)  bf16 [4][NN][32]  (prep -> gather1)
//  z1S  [12.8 .. 25.6M)  bf16 [4][NN][32]  (gather1 -> gemm1, A slice-major)
//  h1b  [25.6 .. 51.2M)  bf16 [NN][256]    (gemm1 -> gemm2, row-major)
//  hbS  [51.2 .. 76.8M)  bf16 [8][NN][32]  (gemm2 MODE3 -> gather2)
//  z2S  [ 0.0 .. 25.6M)  bf16 [8][NN][32]  (gather2 -> gemm3)  over xbS+z1S
//  h2b  [25.6 .. 51.2M)  bf16 [NN][256]    (gemm3 -> gemm4)    over h1b
//  CSR  [76.8M ..)       offs[50001], cursor/counts[50000], srcs[800000], bsum
//  WT   [80.4M ..)       bf16 weights
static const size_t OFF_XBS  = 0;
static const size_t OFF_Z1S  = 12800000;
static const size_t OFF_H1B  = 25600000;
static const size_t OFF_HBS  = 51200000;
static const size_t OFF_Z2S  = 0;
static const size_t OFF_H2B  = 25600000;
static const size_t OFF_OFFS = 76800000;
static const size_t OFF_CNT  = 77000064;
static const size_t OFF_SRC  = 77200128;
static const size_t OFF_BSUM = 80400128;
static const size_t OFF_WT   = 80400512;

extern "C" void kernel_launch(void* const* d_in, const int* in_sizes, int n_in,
                              void* d_out, int out_size, void* d_ws, size_t ws_size,
                              hipStream_t stream)
{
  const float* x    = (const float*)d_in[0];
  const int*   ei   = (const int*)d_in[1];
  const float* W1a  = (const float*)d_in[2];
  const float* b1a  = (const float*)d_in[3];
  const float* W1b  = (const float*)d_in[4];
  const float* b1b  = (const float*)d_in[5];
  const float* eps1 = (const float*)d_in[6];
  const float* W2   = (const float*)d_in[7];
  const float* b2   = (const float*)d_in[8];
  const float* W3   = (const float*)d_in[9];
  const float* b3   = (const float*)d_in[10];

  char* ws = (char*)d_ws;
  unsigned short* xbS  = (unsigned short*)(ws + OFF_XBS);
  unsigned short* z1S  = (unsigned short*)(ws + OFF_Z1S);
  unsigned short* h1b  = (unsigned short*)(ws + OFF_H1B);
  unsigned short* hbS  = (unsigned short*)(ws + OFF_HBS);
  unsigned short* z2S  = (unsigned short*)(ws + OFF_Z2S);
  unsigned short* h2b  = (unsigned short*)(ws + OFF_H2B);
  int*            offs = (int*)(ws + OFF_OFFS);
  int*            cnts = (int*)(ws + OFF_CNT);
  int*            srcs = (int*)(ws + OFF_SRC);
  int*            bsum = (int*)(ws + OFF_BSUM);
  unsigned short* wt   = (unsigned short*)(ws + OFF_WT);
  unsigned short* w1at = wt;                 // [256][128]
  unsigned short* w1bt = wt + 32768;         // [256][256]
  unsigned short* w2t  = wt + 98304;         // [256][256]
  unsigned short* w3t  = wt + 163840;        // [128][256]

  // prep: weights + x->bf16 slice-major + histogram (memset first)
  hipMemsetAsync(cnts, 0, 50000 * sizeof(int), stream);
  k_prep<<<(196608 + NN * 32 + NE) / 256, 256, 0, stream>>>(
      W1a, W1b, W2, W3, wt, x, xbS, ei, cnts);

  // CSR finish
  k_scan_a<<<SCAN_NB, 1024, 0, stream>>>(cnts, offs, bsum);
  k_scan_b<<<SCAN_NB, 1024, 0, stream>>>(bsum, offs, cnts);
  k_scatter<<<(NE + 255) / 256, 256, 0, stream>>>(ei, cnts, srcs);

  // layer 1
  k_gather_sl<4, true><<<NB16 * 4, 256, 0, stream>>>(
      offs, srcs, xbS, x, eps1, z1S);
  dim3 g1(391, 1);
  k_gemm<true, 0, 256, true><<<g1, 512, 0, stream>>>(
      z1S, w1at, b1a, h1b, nullptr, NN, 128, 256);
  k_gemm<true, 3, 256, false><<<g1, 512, 0, stream>>>(
      h1b, w1bt, b1b, hbS, nullptr, NN, 256, 256);

  // layer 2
  k_gather_sl<8, false><<<NB16 * 8, 256, 0, stream>>>(
      offs, srcs, hbS, nullptr, nullptr, z2S);
  k_gemm<true, 0, 256, true><<<g1, 512, 0, stream>>>(
      z2S, w2t, b2, h2b, nullptr, NN, 256, 256);
  k_gemm<false, 2, 128, false><<<g1, 256, 0, stream>>>(
      h2b, w3t, b3, nullptr, (float*)d_out, NN, 256, 128);
}